// Round 11
// baseline (640.485 us; speedup 1.0000x reference)
//
#include <hip/hip_runtime.h>
#include <hip/hip_bf16.h>

#define T_TOK 4096
#define D_DIM 1024
#define E_NUM 8
#define F_DIM 4096
#define NPAIR 8192

#define NTMAX 39          // max tiles: 32 full + 7 expert remainders
#define NMID (NTMAX * 2)  // 78 M-items (128 rows each)

typedef float f32x4 __attribute__((ext_vector_type(4)));
typedef __bf16 bf16x8 __attribute__((ext_vector_type(8)));
typedef unsigned short u16x8 __attribute__((ext_vector_type(8)));

__device__ __forceinline__ unsigned short f2bf(float f) {
    unsigned int u = __float_as_uint(f);
    u += 0x7fffu + ((u >> 16) & 1u);
    return (unsigned short)(u >> 16);
}

// ---------------- Router: one wave per token ----------------
__global__ __launch_bounds__(256) void router_kernel(
    const float* __restrict__ x, const float* __restrict__ noise,
    const float* __restrict__ Wg, const float* __restrict__ bg,
    const float* __restrict__ Wn, const float* __restrict__ bn,
    float* __restrict__ out_noisy, float* __restrict__ out_gate,
    int* __restrict__ tk_idx, float* __restrict__ tk_w)
{
    int lane = threadIdx.x & 63;
    int t = blockIdx.x * 4 + (threadIdx.x >> 6);
    const float* xr = x + (size_t)t * D_DIM;

    float ag[E_NUM] = {}, an[E_NUM] = {};
    for (int it = 0; it < D_DIM / 64; ++it) {
        int d = it * 64 + lane;
        float xv = xr[d];
        float4 g0 = *(const float4*)(Wg + (size_t)d * E_NUM);
        float4 g1 = *(const float4*)(Wg + (size_t)d * E_NUM + 4);
        float4 m0 = *(const float4*)(Wn + (size_t)d * E_NUM);
        float4 m1 = *(const float4*)(Wn + (size_t)d * E_NUM + 4);
        ag[0] += xv * g0.x; ag[1] += xv * g0.y; ag[2] += xv * g0.z; ag[3] += xv * g0.w;
        ag[4] += xv * g1.x; ag[5] += xv * g1.y; ag[6] += xv * g1.z; ag[7] += xv * g1.w;
        an[0] += xv * m0.x; an[1] += xv * m0.y; an[2] += xv * m0.z; an[3] += xv * m0.w;
        an[4] += xv * m1.x; an[5] += xv * m1.y; an[6] += xv * m1.z; an[7] += xv * m1.w;
    }
    #pragma unroll
    for (int off = 32; off > 0; off >>= 1) {
        #pragma unroll
        for (int e = 0; e < E_NUM; ++e) {
            ag[e] += __shfl_xor(ag[e], off);
            an[e] += __shfl_xor(an[e], off);
        }
    }
    if (lane == 0) {
        float nz[E_NUM];
        #pragma unroll
        for (int e = 0; e < E_NUM; ++e) {
            float g = ag[e] + bg[e];
            float nn = an[e] + bn[e];
            float sp = fmaxf(nn, 0.f) + log1pf(expf(-fabsf(nn)));
            float z = g + noise[(size_t)t * E_NUM + e] * sp;
            out_gate[(size_t)t * E_NUM + e] = g;
            out_noisy[(size_t)t * E_NUM + e] = z;
            nz[e] = z;
        }
        int e0 = 0;
        #pragma unroll
        for (int e = 1; e < E_NUM; ++e) if (nz[e] > nz[e0]) e0 = e;
        int e1 = (e0 == 0) ? 1 : 0;
        #pragma unroll
        for (int e = 0; e < E_NUM; ++e) if (e != e0 && nz[e] > nz[e1]) e1 = e;
        float b = expf(nz[e1] - nz[e0]);  // <= 1
        float w0 = 1.f / (1.f + b);
        float w1 = b / (1.f + b);
        tk_idx[t * 2] = e0;  tk_idx[t * 2 + 1] = e1;
        tk_w[t * 2] = w0;    tk_w[t * 2 + 1] = w1;
    }
}

// ---------------- Deterministic group-by-expert (1 block) ----------------
__global__ __launch_bounds__(256) void scan_scatter_kernel(
    const int* __restrict__ tk_idx,
    int* __restrict__ perm, int* __restrict__ meta)
{
    __shared__ int cnt[256][E_NUM];
    __shared__ int soff[E_NUM];
    int tid = threadIdx.x;
    const int PPT = NPAIR / 256;
    int p0 = tid * PPT;

    int c[E_NUM] = {};
    for (int i = 0; i < PPT; ++i) c[tk_idx[p0 + i]]++;
    #pragma unroll
    for (int e = 0; e < E_NUM; ++e) cnt[tid][e] = c[e];
    __syncthreads();

    if (tid < E_NUM) {
        int s = 0;
        for (int j = 0; j < 256; ++j) { int v = cnt[j][tid]; cnt[j][tid] = s; s += v; }
        soff[tid] = s;
    }
    __syncthreads();

    if (tid == 0) {
        int off = 0, nt = 0;
        for (int e = 0; e < E_NUM; ++e) {
            int ce = soff[e];
            meta[1 + e] = off;
            meta[9 + e] = ce;
            for (int j = 0; j < ce; j += 256) {
                meta[32 + nt]  = e;
                meta[160 + nt] = off + j;
                meta[288 + nt] = off + ce;
                nt++;
            }
            off += ce;
        }
        meta[0] = nt;
    }
    __syncthreads();
    if (tid < E_NUM) soff[tid] = meta[1 + tid];
    __syncthreads();

    int pos[E_NUM];
    #pragma unroll
    for (int e = 0; e < E_NUM; ++e) pos[e] = soff[e] + cnt[tid][e];
    for (int i = 0; i < PPT; ++i) {
        int e = tk_idx[p0 + i];
        perm[pos[e]++] = p0 + i;
    }
}

// ---------------- pack x: gathered rows -> k-packet layout ----------------
// xg[tile][kb (D/8=128)][row (256)][8] bf16; row = tile-local grouped row
__global__ __launch_bounds__(256) void pack_x_kernel(
    const float* __restrict__ x, const int* __restrict__ perm,
    const int* __restrict__ meta, unsigned short* __restrict__ xg)
{
    int tile = blockIdx.x;
    if (tile >= meta[0]) return;
    int rs = meta[160 + tile];
    int r = threadIdx.x;
    int pos = rs + r; if (pos >= NPAIR) pos = NPAIR - 1;
    int t = perm[pos] >> 1;
    const float* xr = x + (size_t)t * D_DIM;
    unsigned short* dst = xg + ((size_t)tile * 128) * 256 * 8;
    for (int kb = 0; kb < 128; ++kb) {
        float4 a = *(const float4*)(xr + kb * 8);
        float4 b = *(const float4*)(xr + kb * 8 + 4);
        u16x8 o;
        o[0] = f2bf(a.x); o[1] = f2bf(a.y); o[2] = f2bf(a.z); o[3] = f2bf(a.w);
        o[4] = f2bf(b.x); o[5] = f2bf(b.y); o[6] = f2bf(b.z); o[7] = f2bf(b.w);
        *(u16x8*)(dst + ((size_t)kb * 256 + r) * 8) = o;   // coalesced across threads
    }
}

// ---------------- pack W [E][R][C] f32 -> WP [E][R/8][C][8] bf16 ----------------
__global__ __launch_bounds__(256) void pack_w_kernel(
    const float* __restrict__ W, unsigned short* __restrict__ WP, int R, int C)
{
    int e = blockIdx.z, kb = blockIdx.y;
    int f = blockIdx.x * 256 + threadIdx.x;
    const float* src = W + ((size_t)e * R + kb * 8) * C + f;
    u16x8 o;
    #pragma unroll
    for (int i = 0; i < 8; ++i) o[i] = f2bf(src[(size_t)i * C]);
    *(u16x8*)(WP + (((size_t)e * (R / 8) + kb) * C + f) * 8) = o;
}

// ---------------- FC1: h = gelu(x @ W1 + b1); LDS-free, barrier-free ----------------
// item: 128 M-rows (Mid) x 128 N-cols (n0i). 4 waves: 2M x 2N of 64x64.
__global__ __launch_bounds__(256, 4) void fc1_kernel(
    const unsigned short* __restrict__ xg,    // packets [tile][128][256][8]
    const unsigned short* __restrict__ W1P,   // packets [E][128][F][8]
    const float* __restrict__ b1,
    const int* __restrict__ meta,
    unsigned short* __restrict__ hP)          // packets [tile][512][256][8]
{
    int bid = blockIdx.x;
    int n0i = bid / NMID, Mid = bid % NMID;
    int tile = Mid >> 1, mhalf = Mid & 1;
    if (tile >= meta[0]) return;
    int e = meta[32 + tile], rs = meta[160 + tile], rend = meta[288 + tile];
    int n0 = n0i * 128;

    int lane = threadIdx.x & 63, wv = threadIdx.x >> 6;
    int wm = (wv >> 1) * 64, wn = (wv & 1) * 64;
    int l15 = lane & 15, l16 = lane >> 4;

    const bf16x8* ap = (const bf16x8*)xg + (size_t)tile * (128 * 256)
                     + (size_t)l16 * 256 + (mhalf * 128 + wm + l15);
    const bf16x8* bp = (const bf16x8*)W1P + (size_t)e * (128 * F_DIM)
                     + (size_t)l16 * F_DIM + (n0 + wn + l15);

    f32x4 acc[4][4] = {};
    #pragma unroll 2
    for (int t = 0; t < D_DIM / 32; ++t) {       // 32 steps, kb = 4t + l16
        bf16x8 af[4], bf[4];
        #pragma unroll
        for (int m = 0; m < 4; ++m) af[m] = ap[(size_t)t * 1024 + m * 16];
        #pragma unroll
        for (int n = 0; n < 4; ++n) bf[n] = bp[(size_t)t * 4 * F_DIM + n * 16];
        __builtin_amdgcn_s_setprio(1);
        #pragma unroll
        for (int m = 0; m < 4; ++m)
            #pragma unroll
            for (int n = 0; n < 4; ++n)
                acc[m][n] = __builtin_amdgcn_mfma_f32_16x16x32_bf16(af[m], bf[n], acc[m][n], 0, 0, 0);
        __builtin_amdgcn_s_setprio(0);
    }

    #pragma unroll
    for (int m = 0; m < 4; ++m) {
        #pragma unroll
        for (int j = 0; j < 4; ++j) {
            int r = mhalf * 128 + wm + m * 16 + l16 * 4 + j;
            int p = rs + r;
            if (p >= rend) continue;
            #pragma unroll
            for (int n = 0; n < 4; ++n) {
                int col = n0 + wn + n * 16 + l15;
                float v = acc[m][n][j] + b1[e * F_DIM + col];
                v = 0.5f * v * (1.f + erff(v * 0.70710678118654752f));  // exact GELU
                hP[(((size_t)tile * 512 + (col >> 3)) * 256 + r) * 8 + (col & 7)] = f2bf(v);
            }
        }
    }
}

// ---------------- FC2: out += w*(h @ W2 + b2); LDS-free, barrier-free, splitK=2 ----------------
__global__ __launch_bounds__(256, 4) void fc2_kernel(
    const unsigned short* __restrict__ hP,    // packets [tile][512][256][8]
    const unsigned short* __restrict__ W2P,   // packets [E][512][D][8]
    const float* __restrict__ b2,
    const int* __restrict__ perm,
    const float* __restrict__ tk_w,
    const int* __restrict__ meta,
    float* __restrict__ out)                  // [T][D] fp32 (zeroed)
{
    int bid = blockIdx.x;
    int g = bid / NMID, Mid = bid % NMID;
    int d0i = g >> 1, ks = g & 1;
    int tile = Mid >> 1, mhalf = Mid & 1;
    if (tile >= meta[0]) return;
    int e = meta[32 + tile], rs = meta[160 + tile], rend = meta[288 + tile];
    int kb0 = ks * 256;

    int lane = threadIdx.x & 63, wv = threadIdx.x >> 6;
    int wm = (wv >> 1) * 64, wn = (wv & 1) * 64;
    int l15 = lane & 15, l16 = lane >> 4;

    const bf16x8* ap = (const bf16x8*)hP + ((size_t)tile * 512 + kb0 + l16) * 256
                     + (mhalf * 128 + wm + l15);
    const bf16x8* bp = (const bf16x8*)W2P + ((size_t)e * 512 + kb0 + l16) * D_DIM
                     + (d0i * 128 + wn + l15);

    f32x4 acc[4][4] = {};
    #pragma unroll 2
    for (int t = 0; t < 64; ++t) {               // K = 2048 per split
        bf16x8 af[4], bf[4];
        #pragma unroll
        for (int m = 0; m < 4; ++m) af[m] = ap[(size_t)t * 1024 + m * 16];
        #pragma unroll
        for (int n = 0; n < 4; ++n) bf[n] = bp[(size_t)t * 4 * D_DIM + n * 16];
        __builtin_amdgcn_s_setprio(1);
        #pragma unroll
        for (int m = 0; m < 4; ++m)
            #pragma unroll
            for (int n = 0; n < 4; ++n)
                acc[m][n] = __builtin_amdgcn_mfma_f32_16x16x32_bf16(af[m], bf[n], acc[m][n], 0, 0, 0);
        __builtin_amdgcn_s_setprio(0);
    }

    #pragma unroll
    for (int m = 0; m < 4; ++m) {
        #pragma unroll
        for (int j = 0; j < 4; ++j) {
            int r = mhalf * 128 + wm + m * 16 + l16 * 4 + j;
            int p = rs + r;
            if (p >= rend) continue;
            int pr = perm[p];
            int t2 = pr >> 1;
            float w = tk_w[pr];
            #pragma unroll
            for (int n = 0; n < 4; ++n) {
                int col = d0i * 128 + wn + n * 16 + l15;
                float base = (ks == 0) ? b2[e * D_DIM + col] : 0.f;
                float v = (acc[m][n][j] + base) * w;
                atomicAdd(&out[(size_t)t2 * D_DIM + col], v);
            }
        }
    }
}

extern "C" void kernel_launch(void* const* d_in, const int* in_sizes, int n_in,
                              void* d_out, int out_size, void* d_ws, size_t ws_size,
                              hipStream_t stream)
{
    const float* x     = (const float*)d_in[0];
    const float* noise = (const float*)d_in[1];
    const float* Wg    = (const float*)d_in[2];
    const float* bg    = (const float*)d_in[3];
    const float* Wn    = (const float*)d_in[4];
    const float* bn    = (const float*)d_in[5];
    const float* W1    = (const float*)d_in[6];
    const float* b1    = (const float*)d_in[7];
    const float* W2    = (const float*)d_in[8];
    const float* b2    = (const float*)d_in[9];

    float* out       = (float*)d_out;
    float* out_noisy = out + (size_t)T_TOK * D_DIM;
    float* out_gate  = out_noisy + (size_t)T_TOK * E_NUM;

    char* ws = (char*)d_ws;
    int*   tk_idx = (int*)ws;
    float* tk_w   = (float*)(ws + 32768);
    int*   perm   = (int*)(ws + 65536);
    int*   meta   = (int*)(ws + 98304);
    size_t off = 131072;
    unsigned short* xg  = (unsigned short*)(ws + off); off += (size_t)NTMAX * 128 * 256 * 8 * 2;  // ~20.4 MB
    unsigned short* W1P = (unsigned short*)(ws + off); off += (size_t)E_NUM * 128 * F_DIM * 8 * 2; // 64 MB
    unsigned short* W2P = (unsigned short*)(ws + off); off += (size_t)E_NUM * 512 * D_DIM * 8 * 2; // 64 MB
    unsigned short* hP  = (unsigned short*)(ws + off); off += (size_t)NTMAX * 512 * 256 * 8 * 2;   // ~81.8 MB

    hipMemsetAsync(d_out, 0, (size_t)out_size * sizeof(float), stream);

    router_kernel<<<T_TOK / 4, 256, 0, stream>>>(x, noise, Wg, bg, Wn, bn,
                                                 out_noisy, out_gate, tk_idx, tk_w);
    scan_scatter_kernel<<<1, 256, 0, stream>>>(tk_idx, perm, meta);
    pack_x_kernel<<<NTMAX, 256, 0, stream>>>(x, perm, meta, xg);
    // W2P early (footprint settles before fc1 streams); W1P right before fc1.
    pack_w_kernel<<<dim3(D_DIM / 256, F_DIM / 8, E_NUM), 256, 0, stream>>>(W2, W2P, F_DIM, D_DIM);
    pack_w_kernel<<<dim3(F_DIM / 256, D_DIM / 8, E_NUM), 256, 0, stream>>>(W1, W1P, D_DIM, F_DIM);

    fc1_kernel<<<32 * NMID, 256, 0, stream>>>(xg, W1P, b1, meta, hP);       // 16 n0 ... 32 n0i of 128
    fc2_kernel<<<16 * NMID, 256, 0, stream>>>(hP, W2P, b2, perm, tk_w, meta, out);  // 8 d0i x 2 ks
}

// Round 12
// 549.287 us; speedup vs baseline: 1.1660x; 1.1660x over previous
//
#include <hip/hip_runtime.h>
#include <hip/hip_bf16.h>

#define T_TOK 4096
#define D_DIM 1024
#define E_NUM 8
#define F_DIM 4096
#define NPAIR 8192

#define NTMAX 39   // max tiles of 256 rows: 32 full + 7 expert remainders

typedef float f32x4 __attribute__((ext_vector_type(4)));
typedef __bf16 bf16x8 __attribute__((ext_vector_type(8)));
typedef unsigned short u16x8 __attribute__((ext_vector_type(8)));
typedef unsigned short u16x4 __attribute__((ext_vector_type(4)));

__device__ __forceinline__ unsigned short f2bf(float f) {
    unsigned int u = __float_as_uint(f);
    u += 0x7fffu + ((u >> 16) & 1u);
    return (unsigned short)(u >> 16);
}

typedef const __attribute__((address_space(1))) void GV;
typedef __attribute__((address_space(3))) void LV;

__device__ __forceinline__ void load_lds16(const void* g, void* l) {
    __builtin_amdgcn_global_load_lds((GV*)g, (LV*)l, 16, 0, 0);
}

// Wave-private [64 rows][32 K] bf16 region; row = 64 B = 4 x 16B slots.
// Physical slot s of row r holds logical K-slot (s ^ fsw(r)).
// fsw spreads 16-row x 4-slot frag reads across all 8 bank-groups: exactly
// 2 lanes/bank (free per m136). Same permutation applied on the gload_lds
// SOURCE column (per-lane global addr) and the ds_read side (m173 pattern).
__device__ __forceinline__ int fsw(int r) { return ((r >> 1) ^ (r >> 3)) & 3; }

// ---------------- Router + x->bf16 convert: one wave per token ----------------
__global__ __launch_bounds__(256) void router_convert_kernel(
    const float* __restrict__ x, const float* __restrict__ noise,
    const float* __restrict__ Wg, const float* __restrict__ bg,
    const float* __restrict__ Wn, const float* __restrict__ bn,
    float* __restrict__ out_noisy, float* __restrict__ out_gate,
    int* __restrict__ tk_idx, float* __restrict__ tk_w,
    unsigned short* __restrict__ xb)
{
    int lane = threadIdx.x & 63;
    int t = blockIdx.x * 4 + (threadIdx.x >> 6);
    const float* xr = x + (size_t)t * D_DIM;
    unsigned short* xbr = xb + (size_t)t * D_DIM;

    #pragma unroll
    for (int r = 0; r < 4; ++r) {
        int d = r * 256 + lane * 4;
        float4 v = *(const float4*)(xr + d);
        u16x4 o;
        o[0] = f2bf(v.x); o[1] = f2bf(v.y); o[2] = f2bf(v.z); o[3] = f2bf(v.w);
        *(u16x4*)(xbr + d) = o;
    }

    float ag[E_NUM] = {}, an[E_NUM] = {};
    for (int it = 0; it < D_DIM / 64; ++it) {
        int d = it * 64 + lane;
        float xv = xr[d];
        float4 g0 = *(const float4*)(Wg + (size_t)d * E_NUM);
        float4 g1 = *(const float4*)(Wg + (size_t)d * E_NUM + 4);
        float4 m0 = *(const float4*)(Wn + (size_t)d * E_NUM);
        float4 m1 = *(const float4*)(Wn + (size_t)d * E_NUM + 4);
        ag[0] += xv * g0.x; ag[1] += xv * g0.y; ag[2] += xv * g0.z; ag[3] += xv * g0.w;
        ag[4] += xv * g1.x; ag[5] += xv * g1.y; ag[6] += xv * g1.z; ag[7] += xv * g1.w;
        an[0] += xv * m0.x; an[1] += xv * m0.y; an[2] += xv * m0.z; an[3] += xv * m0.w;
        an[4] += xv * m1.x; an[5] += xv * m1.y; an[6] += xv * m1.z; an[7] += xv * m1.w;
    }
    #pragma unroll
    for (int off = 32; off > 0; off >>= 1) {
        #pragma unroll
        for (int e = 0; e < E_NUM; ++e) {
            ag[e] += __shfl_xor(ag[e], off);
            an[e] += __shfl_xor(an[e], off);
        }
    }
    if (lane == 0) {
        float nz[E_NUM];
        #pragma unroll
        for (int e = 0; e < E_NUM; ++e) {
            float g = ag[e] + bg[e];
            float nn = an[e] + bn[e];
            float sp = fmaxf(nn, 0.f) + log1pf(expf(-fabsf(nn)));
            float z = g + noise[(size_t)t * E_NUM + e] * sp;
            out_gate[(size_t)t * E_NUM + e] = g;
            out_noisy[(size_t)t * E_NUM + e] = z;
            nz[e] = z;
        }
        int e0 = 0;
        #pragma unroll
        for (int e = 1; e < E_NUM; ++e) if (nz[e] > nz[e0]) e0 = e;
        int e1 = (e0 == 0) ? 1 : 0;
        #pragma unroll
        for (int e = 0; e < E_NUM; ++e) if (e != e0 && nz[e] > nz[e1]) e1 = e;
        float b = expf(nz[e1] - nz[e0]);  // <= 1
        float w0 = 1.f / (1.f + b);
        float w1 = b / (1.f + b);
        tk_idx[t * 2] = e0;  tk_idx[t * 2 + 1] = e1;
        tk_w[t * 2] = w0;    tk_w[t * 2 + 1] = w1;
    }
}

// ---------------- Deterministic group-by-expert (1 block) ----------------
__global__ __launch_bounds__(256) void scan_scatter_kernel(
    const int* __restrict__ tk_idx,
    int* __restrict__ perm, int* __restrict__ meta)
{
    __shared__ int cnt[256][E_NUM];
    __shared__ int soff[E_NUM];
    int tid = threadIdx.x;
    const int PPT = NPAIR / 256;
    int p0 = tid * PPT;

    int c[E_NUM] = {};
    for (int i = 0; i < PPT; ++i) c[tk_idx[p0 + i]]++;
    #pragma unroll
    for (int e = 0; e < E_NUM; ++e) cnt[tid][e] = c[e];
    __syncthreads();

    if (tid < E_NUM) {
        int s = 0;
        for (int j = 0; j < 256; ++j) { int v = cnt[j][tid]; cnt[j][tid] = s; s += v; }
        soff[tid] = s;
    }
    __syncthreads();

    if (tid == 0) {
        int off = 0, nt = 0;
        for (int e = 0; e < E_NUM; ++e) {
            int ce = soff[e];
            meta[1 + e] = off;
            meta[9 + e] = ce;
            for (int j = 0; j < ce; j += 256) {
                meta[32 + nt]  = e;
                meta[160 + nt] = off + j;
                meta[288 + nt] = off + ce;
                nt++;
            }
            off += ce;
        }
        meta[0] = nt;
    }
    __syncthreads();
    if (tid < E_NUM) soff[tid] = meta[1 + tid];
    __syncthreads();

    int pos[E_NUM];
    #pragma unroll
    for (int e = 0; e < E_NUM; ++e) pos[e] = soff[e] + cnt[tid][e];
    for (int i = 0; i < PPT; ++i) {
        int e = tk_idx[p0 + i];
        perm[pos[e]++] = p0 + i;
    }
}

// ---------------- W [E][R][C] f32 -> WT [E][C][R] bf16, 64x64 tiles ----------------
__global__ __launch_bounds__(256) void transpose_kernel(
    const float* __restrict__ W, unsigned short* __restrict__ WT, int R, int C)
{
    __shared__ float tile[64][65];
    int e = blockIdx.z;
    int c0 = blockIdx.x * 64, r0 = blockIdx.y * 64;
    int tx = threadIdx.x & 15, ty = threadIdx.x >> 4;
    const float* src = W + (size_t)e * R * C;
    #pragma unroll
    for (int j = 0; j < 4; ++j) {
        int r = ty + 16 * j;
        float4 v = *(const float4*)(src + (size_t)(r0 + r) * C + c0 + tx * 4);
        *(float4*)&tile[r][tx * 4] = v;
    }
    __syncthreads();
    unsigned short* dst = WT + (size_t)e * C * R;
    int sx = threadIdx.x & 7, sy = threadIdx.x >> 3;
    #pragma unroll
    for (int j = 0; j < 2; ++j) {
        int c = sy + 32 * j;
        u16x8 o;
        #pragma unroll
        for (int k = 0; k < 8; ++k) o[k] = f2bf(tile[sx * 8 + k][c]);
        *(u16x8*)(dst + (size_t)(c0 + c) * R + r0 + sx * 8) = o;
    }
}

// ---- wave-local K-loop: no block barriers. Each wave: private LDS 8 KB,
//      stage(t+1) issued after frags of t are in registers, 16 MFMA per step.
#define WAVE_GEMM_LOOP(NT)                                                              \
    for (int t = 0; t < (NT); ++t) {                                                    \
        asm volatile("s_waitcnt vmcnt(0)" ::: "memory");                                \
        __builtin_amdgcn_sched_barrier(0);                                              \
        bf16x8 af[4], bf[4];                                                            \
        _Pragma("unroll")                                                               \
        for (int m_ = 0; m_ < 4; ++m_) {                                                \
            int r_ = m_ * 16 + l15;                                                     \
            af[m_] = *(const bf16x8*)((const char*)la + r_ * 64 + ((l16 ^ fsw(r_)) << 4)); \
        }                                                                               \
        _Pragma("unroll")                                                               \
        for (int n_ = 0; n_ < 4; ++n_) {                                                \
            int r_ = n_ * 16 + l15;                                                     \
            bf[n_] = *(const bf16x8*)((const char*)lb + r_ * 64 + ((l16 ^ fsw(r_)) << 4)); \
        }                                                                               \
        asm volatile("s_waitcnt lgkmcnt(0)" ::: "memory");                              \
        __builtin_amdgcn_sched_barrier(0);                                              \
        if (t + 1 < (NT)) {                                                             \
            int k0_ = (t + 1) * 32;                                                     \
            _Pragma("unroll")                                                           \
            for (int i_ = 0; i_ < 4; ++i_) {                                            \
                load_lds16(ap[i_] + k0_, la + i_ * 512);                                \
                load_lds16(bp[i_] + k0_, lb + i_ * 512);                                \
            }                                                                           \
        }                                                                               \
        __builtin_amdgcn_s_setprio(1);                                                  \
        _Pragma("unroll")                                                               \
        for (int m_ = 0; m_ < 4; ++m_)                                                  \
            _Pragma("unroll")                                                           \
            for (int n_ = 0; n_ < 4; ++n_)                                              \
                acc[m_][n_] = __builtin_amdgcn_mfma_f32_16x16x32_bf16(af[m_], bf[n_],   \
                                                                      acc[m_][n_], 0, 0, 0); \
        __builtin_amdgcn_s_setprio(0);                                                  \
    }

// ---------------- FC1: h = gelu(x @ W1 + b1); wave-local, barrier-free ----------------
// block = 4 waves (2x2), covers 128 rows x 128 cols. Grid 8 XCD x (4 n x 78 mb).
__global__ __launch_bounds__(256, 4) void fc1_kernel(
    const unsigned short* __restrict__ xb,    // [T][D] bf16
    const unsigned short* __restrict__ W1T,   // [E][F][D] bf16
    const float* __restrict__ b1,
    const int* __restrict__ perm,
    const int* __restrict__ meta,
    unsigned short* __restrict__ h)           // [NPAIR][F] bf16
{
    int nt = meta[0];
    int bid = blockIdx.x;
    int xcd = bid & 7;
    int idx = bid >> 3;                       // [0, 312)
    int n0i = xcd * 4 + (idx & 3);            // XCD owns 4 n-blocks: B-slice L2-resident
    int mb  = idx >> 2;                       // [0, 78)
    int tile = mb >> 1, mhalf = mb & 1;
    if (tile >= nt) return;
    int e = meta[32 + tile], rs = meta[160 + tile], rend = meta[288 + tile];

    __shared__ __align__(16) unsigned short As[4][2048];   // 4 KB per wave
    __shared__ __align__(16) unsigned short Bs[4][2048];

    int lane = threadIdx.x & 63, wv = threadIdx.x >> 6;
    int wr = wv >> 1, wc = wv & 1;
    int l15 = lane & 15, l16 = lane >> 4;

    int rowA = mhalf * 128 + wr * 64;         // tile-local base row of wave's A
    int colB = n0i * 128 + wc * 64;           // global base col of wave's B

    const unsigned short* ap[4];
    const unsigned short* bp[4];
    #pragma unroll
    for (int i = 0; i < 4; ++i) {
        int lr = i * 16 + (lane >> 2);        // local row 0..63 (lane>>2 of this instr)
        int csw = ((lane & 3) ^ fsw(lr)) * 8; // pre-swizzled source K-col (shorts)
        int pos = rs + rowA + lr; if (pos >= NPAIR) pos = NPAIR - 1;
        ap[i] = xb + (size_t)(perm[pos] >> 1) * D_DIM + csw;
        bp[i] = W1T + ((size_t)e * F_DIM + colB + lr) * D_DIM + csw;
    }
    unsigned short* la = As[wv];
    unsigned short* lb = Bs[wv];

    f32x4 acc[4][4] = {};

    #pragma unroll
    for (int i = 0; i < 4; ++i) { load_lds16(ap[i], la + i * 512); load_lds16(bp[i], lb + i * 512); }

    WAVE_GEMM_LOOP(D_DIM / 32)   // 32 steps

    #pragma unroll
    for (int m = 0; m < 4; ++m) {
        #pragma unroll
        for (int j = 0; j < 4; ++j) {
            int p = rs + rowA + m * 16 + l16 * 4 + j;
            if (p >= rend) continue;
            #pragma unroll
            for (int n = 0; n < 4; ++n) {
                int col = colB + n * 16 + l15;
                float v = acc[m][n][j] + b1[e * F_DIM + col];
                v = 0.5f * v * (1.f + erff(v * 0.70710678118654752f));  // exact GELU
                h[(size_t)p * F_DIM + col] = f2bf(v);
            }
        }
    }
}

// ---------------- FC2: out += w*(h @ W2 + b2); wave-local, splitK=2 ----------------
// Grid 8 XCD x (78 mb x 2 ks); each XCD owns one 128-col W2 panel (1 MB, L2).
__global__ __launch_bounds__(256, 4) void fc2_kernel(
    const unsigned short* __restrict__ h,     // [NPAIR][F] bf16 (grouped rows contiguous)
    const unsigned short* __restrict__ W2T,   // [E][D][F] bf16
    const float* __restrict__ b2,
    const int* __restrict__ perm,
    const float* __restrict__ tk_w,
    const int* __restrict__ meta,
    float* __restrict__ out)                  // [T][D] fp32 (zeroed)
{
    int nt = meta[0];
    int bid = blockIdx.x;
    int xcd = bid & 7;
    int idx = bid >> 3;                       // [0, 156)
    int n0i = xcd;                            // 8 d-blocks of 128 == 8 XCDs
    int ks  = idx & 1;
    int mb  = idx >> 1;                       // [0, 78)
    int tile = mb >> 1, mhalf = mb & 1;
    if (tile >= nt) return;
    int e = meta[32 + tile], rs = meta[160 + tile], rend = meta[288 + tile];
    int kbeg = ks * (F_DIM / 2);

    __shared__ __align__(16) unsigned short As[4][2048];
    __shared__ __align__(16) unsigned short Bs[4][2048];

    int lane = threadIdx.x & 63, wv = threadIdx.x >> 6;
    int wr = wv >> 1, wc = wv & 1;
    int l15 = lane & 15, l16 = lane >> 4;

    int rowA = mhalf * 128 + wr * 64;
    int colB = n0i * 128 + wc * 64;

    const unsigned short* ap[4];
    const unsigned short* bp[4];
    #pragma unroll
    for (int i = 0; i < 4; ++i) {
        int lr = i * 16 + (lane >> 2);
        int csw = ((lane & 3) ^ fsw(lr)) * 8;
        int pos = rs + rowA + lr; if (pos >= NPAIR) pos = NPAIR - 1;
        ap[i] = h + (size_t)pos * F_DIM + kbeg + csw;           // grouped rows contiguous
        bp[i] = W2T + ((size_t)e * D_DIM + colB + lr) * F_DIM + kbeg + csw;
    }
    unsigned short* la = As[wv];
    unsigned short* lb = Bs[wv];

    f32x4 acc[4][4] = {};

    #pragma unroll
    for (int i = 0; i < 4; ++i) { load_lds16(ap[i], la + i * 512); load_lds16(bp[i], lb + i * 512); }

    WAVE_GEMM_LOOP((F_DIM / 2) / 32)   // 64 steps

    #pragma unroll
    for (int m = 0; m < 4; ++m) {
        #pragma unroll
        for (int j = 0; j < 4; ++j) {
            int p = rs + rowA + m * 16 + l16 * 4 + j;
            if (p >= rend) continue;
            int pr = perm[p];
            int t2 = pr >> 1;
            float w = tk_w[pr];
            #pragma unroll
            for (int n = 0; n < 4; ++n) {
                int col = colB + n * 16 + l15;
                float base = (ks == 0) ? b2[e * D_DIM + col] : 0.f;
                float v = (acc[m][n][j] + base) * w;
                atomicAdd(&out[(size_t)t2 * D_DIM + col], v);
            }
        }
    }
}

extern "C" void kernel_launch(void* const* d_in, const int* in_sizes, int n_in,
                              void* d_out, int out_size, void* d_ws, size_t ws_size,
                              hipStream_t stream)
{
    const float* x     = (const float*)d_in[0];
    const float* noise = (const float*)d_in[1];
    const float* Wg    = (const float*)d_in[2];
    const float* bg    = (const float*)d_in[3];
    const float* Wn    = (const float*)d_in[4];
    const float* bn    = (const float*)d_in[5];
    const float* W1    = (const float*)d_in[6];
    const float* b1    = (const float*)d_in[7];
    const float* W2    = (const float*)d_in[8];
    const float* b2    = (const float*)d_in[9];

    float* out       = (float*)d_out;
    float* out_noisy = out + (size_t)T_TOK * D_DIM;
    float* out_gate  = out_noisy + (size_t)T_TOK * E_NUM;

    char* ws = (char*)d_ws;
    int*   tk_idx = (int*)ws;
    float* tk_w   = (float*)(ws + 32768);
    int*   perm   = (int*)(ws + 65536);
    int*   meta   = (int*)(ws + 98304);
    size_t off = 131072;
    unsigned short* xb   = (unsigned short*)(ws + off); off += (size_t)T_TOK * D_DIM * 2;
    unsigned short* W1T  = (unsigned short*)(ws + off); off += (size_t)E_NUM * F_DIM * D_DIM * 2;
    unsigned short* W2T  = (unsigned short*)(ws + off); off += (size_t)E_NUM * D_DIM * F_DIM * 2;
    unsigned short* hbuf = (unsigned short*)(ws + off); off += (size_t)NPAIR * F_DIM * 2;

    hipMemsetAsync(d_out, 0, (size_t)out_size * sizeof(float), stream);

    router_convert_kernel<<<T_TOK / 4, 256, 0, stream>>>(x, noise, Wg, bg, Wn, bn,
                                                         out_noisy, out_gate, tk_idx, tk_w, xb);
    scan_scatter_kernel<<<1, 256, 0, stream>>>(tk_idx, perm, meta);
    // W2T early (footprint settles before fc1 streams); W1T right before fc1.
    transpose_kernel<<<dim3(D_DIM / 64, F_DIM / 64, E_NUM), 256, 0, stream>>>(W2, W2T, F_DIM, D_DIM);
    transpose_kernel<<<dim3(F_DIM / 64, D_DIM / 64, E_NUM), 256, 0, stream>>>(W1, W1T, D_DIM, F_DIM);

    fc1_kernel<<<8 * 4 * (NTMAX * 2), 256, 0, stream>>>(xb, W1T, b1, perm, meta, hbuf);   // 2496
    fc2_kernel<<<8 * 2 * (NTMAX * 2), 256, 0, stream>>>(hbuf, W2T, b2, perm, tk_w, meta, out);  // 1248
}